// Round 9
// baseline (221.067 us; speedup 1.0000x reference)
//
#include <hip/hip_runtime.h>
#include <hip/hip_bf16.h>

// Fused adapter: out = relu(LN(x) @ Wd + bd) @ Wu + bu
// LN folded into GEMM1:  down = rs*(x @ (gamma⊙Wd)) - rs*mu*s + t
// R8 (resubmitted R9 after acquisition timeout): attack per-CU memory-level
// parallelism on BOTH factors.
// Evidence: R2-R7 all pinned at 1.7-2.3 TB/s; R7 (contiguous DMA) = 16
// waves/CU x ~2 outstanding x 256B = 8KB/CU = 2.3 TB/s by Little's law —
// exactly observed. m135 proves HW takes >=8 outstanding loads/wave; the
// depth-2 is compiler sinking (R4: VGPR=40) + shallow per-wave DMA service.
//  - deep per-wave bursts: 12 global float4 loads into registers, single-
//    buffered, asm "memory" fence between issue and consume (no loop-carried
//    dbuf => compiler-friendly; loads of next burst can still float up)
//  - 16 waves/CU: 2-way K-split (wave = 16 rows x 384 cols), grid 1024x256,
//    launch_bounds(256,4) to force VGPR<=128
//  - K-split partials (acc, LN stats) combined via small LDS exchange
//  - GEMM2 and all fragment mappings identical to R3/R7 (re-derived)

#define D_MODEL 768
#define KB      64
#define NTHR    256
#define PPAD    72      // p_s row stride in shorts (64 + 8 pad)

typedef __attribute__((ext_vector_type(8))) short    bf16x8;
typedef __attribute__((ext_vector_type(4))) float    f32x4;
typedef __attribute__((ext_vector_type(4))) unsigned short us4;

static __device__ __forceinline__ unsigned short f2bf(float f) {
  unsigned int u = __builtin_bit_cast(unsigned int, f);
  unsigned int r = u + 0x7FFFu + ((u >> 16) & 1u);
  return (unsigned short)(r >> 16);
}

static __device__ __forceinline__ bf16x8 pack_bf8(const f32x4 a, const f32x4 b) {
  union { __hip_bfloat162 h2[4]; bf16x8 v; } u;
  u.h2[0] = __float22bfloat162_rn({a[0], a[1]});
  u.h2[1] = __float22bfloat162_rn({a[2], a[3]});
  u.h2[2] = __float22bfloat162_rn({b[0], b[1]});
  u.h2[3] = __float22bfloat162_rn({b[2], b[3]});
  return u.v;
}

// ---------------- prep kernel: 49 blocks x 1024 thr (unchanged) ----------------
__global__ void __launch_bounds__(1024) adapter_prep(
    const float* __restrict__ wd,
    const float* __restrict__ wu,
    const float* __restrict__ gamma,
    const float* __restrict__ beta,
    const float* __restrict__ bdown,
    unsigned short* __restrict__ wdT,
    unsigned short* __restrict__ wuT,
    float* __restrict__ s_arr,
    float* __restrict__ t_arr) {
  const int b = blockIdx.x;
  const int t = threadIdx.x;
  if (b < 48) {
    const int i = b * 1024 + t;         // 0..49151
    const int k1 = i / D_MODEL;
    const int d1 = i - k1 * D_MODEL;
    wdT[i] = f2bf(gamma[d1] * wd[(size_t)d1 * KB + k1]);
    const int d2 = i >> 6;
    const int k2 = i & 63;
    wuT[i] = f2bf(wu[(size_t)k2 * D_MODEL + d2]);
  } else {
    const int k = t & 63;
    const int c = t >> 6;               // 0..15, 48 d's each
    float ss = 0.f, tt = 0.f;
    const int d0 = c * 48;
    #pragma unroll 4
    for (int d = d0; d < d0 + 48; ++d) {
      const float w = wd[(size_t)d * KB + k];
      ss = fmaf(gamma[d], w, ss);
      tt = fmaf(beta[d],  w, tt);
    }
    __shared__ float ps[16][64], pt[16][64];
    ps[c][k] = ss; pt[c][k] = tt;
    __syncthreads();
    if (t < 64) {
      float S = 0.f, T = 0.f;
      #pragma unroll
      for (int q = 0; q < 16; ++q) { S += ps[q][t]; T += pt[q][t]; }
      s_arr[t] = S;
      t_arr[t] = T + bdown[t];
    }
  }
}

// ---------------- main fused kernel ----------------
// Block: 32 rows, 4 waves. Wave w: row-tile rt=w>>1 (16 rows), K-half kh=w&1
// (384 cols). GEMM1 partials combined with partner wave (w^1) via LDS.
__global__ void __launch_bounds__(NTHR, 4) adapter_main(
    const float* __restrict__ x,
    const float* __restrict__ s_arr,
    const float* __restrict__ t_arr,
    const unsigned short* __restrict__ wdT,
    const unsigned short* __restrict__ wuT,
    const float* __restrict__ b_up,
    float* __restrict__ out) {

  __shared__ float sst[4][64][2];                       // 2 KiB stats exchange
  __shared__ __align__(16) float aex[4][2][64][4];      // 8 KiB acc exchange
  __shared__ unsigned short p_s[2][16][PPAD];           // 4.5 KiB

  const int t  = threadIdx.x;
  const int w  = t >> 6;
  const int l  = t & 63;
  const int lr = l & 15;
  const int lg = l >> 4;
  const int rt = w >> 1;       // row-tile
  const int kh = w & 1;        // K-half
  const int rb = blockIdx.x * 32 + 16 * rt;

  // x B-frag base: x[rb+lr][384kh + 32kkl + 8lg + e]
  const float* xp = x + (size_t)(rb + lr) * D_MODEL + 384 * kh + 8 * lg;
  // wdT A-frag base: wdT[16c+lr][384kh + 32kkl + 8lg + e]
  const unsigned short* wp = wdT + (size_t)lr * D_MODEL + 384 * kh + 8 * lg;

  f32x4 acc0 = {0.f,0.f,0.f,0.f}, acc1 = {0.f,0.f,0.f,0.f};
  f32x4 acc2 = {0.f,0.f,0.f,0.f}, acc3 = {0.f,0.f,0.f,0.f};
  float s1 = 0.f, s2 = 0.f;

  // ---- GEMM1: 2 bursts x 6 kk; 12 float4 loads issued back-to-back ----
  #pragma unroll
  for (int half = 0; half < 2; ++half) {
    f32x4 xv[6][2];
    #pragma unroll
    for (int j = 0; j < 6; ++j) {
      const float* p = xp + 32 * (6 * half + j);
      xv[j][0] = *(const f32x4*)(p);
      xv[j][1] = *(const f32x4*)(p + 4);
    }
    // compiler fence: loads above cannot sink below; consume (VALU/MFMA)
    // stays after; next burst's loads may still float up past the consume.
    asm volatile("" ::: "memory");
    #pragma unroll
    for (int j = 0; j < 6; ++j) {
      const int kkl = 6 * half + j;
      const f32x4 v0 = xv[j][0];
      const f32x4 v1 = xv[j][1];
      s1 += (v0[0] + v0[1]) + (v0[2] + v0[3]) + (v1[0] + v1[1]) + (v1[2] + v1[3]);
      s2 = fmaf(v0[0], v0[0], s2); s2 = fmaf(v0[1], v0[1], s2);
      s2 = fmaf(v0[2], v0[2], s2); s2 = fmaf(v0[3], v0[3], s2);
      s2 = fmaf(v1[0], v1[0], s2); s2 = fmaf(v1[1], v1[1], s2);
      s2 = fmaf(v1[2], v1[2], s2); s2 = fmaf(v1[3], v1[3], s2);
      const bf16x8 xf = pack_bf8(v0, v1);
      const unsigned short* wq = wp + 32 * kkl;
      acc0 = __builtin_amdgcn_mfma_f32_16x16x32_bf16(*(const bf16x8*)(wq),                    xf, acc0, 0, 0, 0);
      acc1 = __builtin_amdgcn_mfma_f32_16x16x32_bf16(*(const bf16x8*)(wq + 16 * D_MODEL),     xf, acc1, 0, 0, 0);
      acc2 = __builtin_amdgcn_mfma_f32_16x16x32_bf16(*(const bf16x8*)(wq + 32 * D_MODEL),     xf, acc2, 0, 0, 0);
      acc3 = __builtin_amdgcn_mfma_f32_16x16x32_bf16(*(const bf16x8*)(wq + 48 * D_MODEL),     xf, acc3, 0, 0, 0);
    }
  }

  // ---- exchange partials with partner wave (same rt, other kh) ----
  sst[w][l][0] = s1;
  sst[w][l][1] = s2;
  if (kh == 0) {            // owns c-tiles {0,1}; ships {2,3}
    *(f32x4*)aex[w][0][l] = acc2;
    *(f32x4*)aex[w][1][l] = acc3;
  } else {                  // owns {2,3}; ships {0,1}
    *(f32x4*)aex[w][0][l] = acc0;
    *(f32x4*)aex[w][1][l] = acc1;
  }
  __syncthreads();

  const int pw = w ^ 1;
  s1 += sst[pw][l][0];
  s2 += sst[pw][l][1];
  s1 += __shfl_xor(s1, 16); s1 += __shfl_xor(s1, 32);
  s2 += __shfl_xor(s2, 16); s2 += __shfl_xor(s2, 32);
  const float mu  = s1 * (1.0f / 768.0f);
  const float var = s2 * (1.0f / 768.0f) - mu * mu;
  const float rs  = rsqrtf(var + 1e-5f);
  const float nm  = -rs * mu;

  const f32x4 pe0 = *(const f32x4*)aex[pw][0][l];   // partner's partial of my tiles
  const f32x4 pe1 = *(const f32x4*)aex[pw][1][l];
  f32x4 f0, f1; int cbase;
  if (kh == 0) { f0 = acc0 + pe0; f1 = acc1 + pe1; cbase = 0; }
  else         { f0 = acc2 + pe0; f1 = acc3 + pe1; cbase = 2; }

  // ---- epilogue: LN correction + ReLU -> p_s[rt][row lr][col 16co+4lg+j] ----
  #pragma unroll
  for (int i = 0; i < 2; ++i) {
    const f32x4 a = i ? f1 : f0;
    const int co = cbase + i;
    const float4 sv = *(const float4*)(s_arr + 16 * co + 4 * lg);
    const float4 tv = *(const float4*)(t_arr + 16 * co + 4 * lg);
    us4 pk;
    pk.x = f2bf(fmaxf(fmaf(rs, a[0], fmaf(nm, sv.x, tv.x)), 0.f));
    pk.y = f2bf(fmaxf(fmaf(rs, a[1], fmaf(nm, sv.y, tv.y)), 0.f));
    pk.z = f2bf(fmaxf(fmaf(rs, a[2], fmaf(nm, sv.z, tv.z)), 0.f));
    pk.w = f2bf(fmaxf(fmaf(rs, a[3], fmaf(nm, sv.w, tv.w)), 0.f));
    *(us4*)&p_s[rt][lr][16 * co + 4 * lg] = pk;
  }
  __syncthreads();

  // ---- GEMM2: out[16 rows] = P(16x64) @ Wu; wave covers 24 N-tiles ----
  const bf16x8 pa0 = *(const bf16x8*)&p_s[rt][lr][8 * lg];        // k 0..31
  const bf16x8 pa1 = *(const bf16x8*)&p_s[rt][lr][32 + 8 * lg];   // k 32..63
  float* op = out + (size_t)(rb + 4 * lg) * D_MODEL + lr;
  const int n0 = 24 * kh;

  #pragma unroll 6
  for (int i = 0; i < 24; ++i) {
    const int cn = 16 * (n0 + i);
    const unsigned short* bp = wuT + (size_t)(cn + lr) * KB + 8 * lg;
    f32x4 c0 = {0.f, 0.f, 0.f, 0.f};
    c0 = __builtin_amdgcn_mfma_f32_16x16x32_bf16(pa0, *(const bf16x8*)(bp),      c0, 0, 0, 0);
    c0 = __builtin_amdgcn_mfma_f32_16x16x32_bf16(pa1, *(const bf16x8*)(bp + 32), c0, 0, 0, 0);
    const float bu = b_up[cn + lr];
    op[(size_t)0 * D_MODEL + cn] = c0[0] + bu;
    op[(size_t)1 * D_MODEL + cn] = c0[1] + bu;
    op[(size_t)2 * D_MODEL + cn] = c0[2] + bu;
    op[(size_t)3 * D_MODEL + cn] = c0[3] + bu;
  }
}

// ---------------- launch ----------------
extern "C" void kernel_launch(void* const* d_in, const int* in_sizes, int n_in,
                              void* d_out, int out_size, void* d_ws, size_t ws_size,
                              hipStream_t stream) {
  const float* x     = (const float*)d_in[0];
  const float* gamma = (const float*)d_in[1];
  const float* beta  = (const float*)d_in[2];
  const float* wd    = (const float*)d_in[3];
  const float* bdown = (const float*)d_in[4];
  const float* wu    = (const float*)d_in[5];
  const float* bup   = (const float*)d_in[6];
  float* out = (float*)d_out;

  char* ws = (char*)d_ws;
  unsigned short* wdT = (unsigned short*)ws;                    // 96 KiB
  unsigned short* wuT = (unsigned short*)(ws + 98304);          // 96 KiB
  float* s_arr = (float*)(ws + 196608);                         // 256 B
  float* t_arr = (float*)(ws + 196864);                         // 256 B

  const int rows = in_sizes[0] / D_MODEL;       // 32768

  adapter_prep<<<49, 1024, 0, stream>>>(wd, wu, gamma, beta, bdown,
                                        wdT, wuT, s_arr, t_arr);
  adapter_main<<<rows / 32, NTHR, 0, stream>>>(x, s_arr, t_arr, wdT, wuT, bup, out);
}